// Round 10
// baseline (1914.994 us; speedup 1.0000x reference)
//
#include <hip/hip_runtime.h>
#include <hip/hip_bf16.h>

// Problem constants
#define T_TOKENS 8192   // SEQ*BS
#define H_DIM 2048
#define I_DIM 4096
#define E_EXP 8
#define PAD_ROWS 9216   // 8192 + 8*128 worst-case padded segment total

typedef __bf16 bf16x8 __attribute__((ext_vector_type(8)));
typedef float floatx4 __attribute__((ext_vector_type(4)));
typedef unsigned short ushort8 __attribute__((ext_vector_type(8)));

__device__ __forceinline__ unsigned short f2bf(float f) {
  // round-to-nearest-even f32 -> bf16 (inputs are finite; no NaN handling needed)
  union { float f; unsigned int i; } c; c.f = f;
  unsigned int x = c.i;
  unsigned int r = x + 0x7fffu + ((x >> 16) & 1u);
  return (unsigned short)(r >> 16);
}

// async global->LDS, 16B per lane. LDS dest = wave-uniform base + lane*16.
// Global source is PER-LANE (guide §5 / m173).
__device__ __forceinline__ void gload_lds16(const void* g, void* l) {
  __builtin_amdgcn_global_load_lds(
      (const __attribute__((address_space(1))) void*)g,
      (__attribute__((address_space(3))) void*)l, 16, 0, 0);
}

// ---------------------------------------------------------------------------
// K1: router logits + argmax + fused fp32->bf16 conversion of hidden.
// One wave per token; hidden read ONCE. hdr zeroed via hipMemsetAsync.
// ---------------------------------------------------------------------------
__global__ __launch_bounds__(256) void router_kernel(const float* __restrict__ x,
                                                     const float* __restrict__ rw,
                                                     unsigned short* __restrict__ xb,
                                                     int* __restrict__ idx,
                                                     int* __restrict__ hdr) {
  const int lane = threadIdx.x & 63;
  const int t = blockIdx.x * 4 + (threadIdx.x >> 6);
  const float* xr = x + (size_t)t * H_DIM;
  unsigned short* xbr = xb + (size_t)t * H_DIM;
  float acc[8];
#pragma unroll
  for (int e = 0; e < 8; ++e) acc[e] = 0.f;
#pragma unroll
  for (int j = 0; j < 8; ++j) {
    const int c0 = (lane + j * 64) * 4;
    floatx4 v = *(const floatx4*)(xr + c0);
    ushort4 o;
    o.x = f2bf(v[0]); o.y = f2bf(v[1]); o.z = f2bf(v[2]); o.w = f2bf(v[3]);
    *(ushort4*)(xbr + c0) = o;
#pragma unroll
    for (int cc = 0; cc < 4; ++cc) {
      const float h = v[cc];
      floatx4 r0 = *(const floatx4*)(rw + (size_t)(c0 + cc) * 8);
      floatx4 r1 = *(const floatx4*)(rw + (size_t)(c0 + cc) * 8 + 4);
#pragma unroll
      for (int e = 0; e < 4; ++e) { acc[e] += h * r0[e]; acc[e + 4] += h * r1[e]; }
    }
  }
#pragma unroll
  for (int off = 32; off > 0; off >>= 1)
#pragma unroll
    for (int e = 0; e < 8; ++e) acc[e] += __shfl_xor(acc[e], off, 64);
  if (lane == 0) {
    int best = 0; float bv = acc[0];
#pragma unroll
    for (int e = 1; e < 8; ++e) if (acc[e] > bv) { bv = acc[e]; best = e; }
    idx[t] = best;
    atomicAdd(&hdr[best], 1);
  }
}

// ---------------------------------------------------------------------------
// K2: segment bases (128-aligned) + rows[] sentinel init
// ---------------------------------------------------------------------------
__global__ __launch_bounds__(256) void setup_kernel(int* __restrict__ hdr,
                                                    int* __restrict__ rows) {
  if (threadIdx.x == 0) {
    int b = 0;
    for (int e = 0; e < 8; ++e) {
      hdr[16 + e] = b;
      b += ((hdr[e] + 127) >> 7) << 7;
    }
  }
  for (int i = threadIdx.x; i < PAD_ROWS; i += 256) rows[i] = -1;
}

// ---------------------------------------------------------------------------
// K3: scatter token ids into per-expert segments
// ---------------------------------------------------------------------------
__global__ __launch_bounds__(256) void scatter_kernel(const int* __restrict__ idx,
                                                      int* __restrict__ hdr,
                                                      int* __restrict__ rows) {
  int t = blockIdx.x * 256 + threadIdx.x;
  int e = idx[t];
  int p = atomicAdd(&hdr[8 + e], 1);
  rows[hdr[16 + e] + p] = t;
}

// ---------------------------------------------------------------------------
// K5: fused gate+up grouped GEMM reading fp32 WEIGHTS DIRECTLY (round-2
// structure, 356us measured, 0 bank conflicts). The entire weight prepass
// is deleted: pre-tiled bf16 gave an identical GEMM time (352 vs 356) while
// costing ~430us of cvt dispatch time + 800MB extra HBM traffic.
// 128x128 tile, BK=64, 4 waves, dual acc; A (bf16 tokens) staged once via
// global_load_lds w16 with XOR-swizzled source; B fp32 staged via reg-loads
// (512B/row coalesced), f2bf, transposed ds_write into [n][72] padded tile
// (+8 pad: 0 conflicts measured). 64 MFMA per barrier pair.
// Epilogue: inter = silu(g_f32) * u.
// ---------------------------------------------------------------------------
__global__ __launch_bounds__(256, 2) void moe_gemm_gu(
    const unsigned short* __restrict__ A,
    const float* __restrict__ Bg,
    const float* __restrict__ Bu,
    const int* __restrict__ hdr,
    const int* __restrict__ rows,
    unsigned short* __restrict__ inter) {
  const int e = blockIdx.z;
  const int cnt = hdr[e];
  if ((int)blockIdx.y * 128 >= cnt) return;  // uniform early exit
  const int seg = hdr[16 + e];

  const int tid = threadIdx.x;
  const int lane = tid & 63;
  const int wv = tid >> 6;
  const int wm = (wv & 1) * 64;
  const int wn = (wv >> 1) * 64;
  const int q = lane >> 4;
  const int l15 = lane & 15;

  __shared__ unsigned short sA[128 * 64];   // [m][64k] bf16, slot-swizzled
  __shared__ unsigned short sBg[128 * 72];  // [n][k] bf16 transposed, +8 pad
  __shared__ unsigned short sBu[128 * 72];

  // ---- A staging coords (XOR-swizzled source, linear LDS dest) ----
  const int lr = lane >> 3;            // row within 8-row chunk == row&7
  const int colsw = (lane & 7) ^ lr;   // pre-swizzled 8-elem slot index
  const unsigned short* aptr[4];
#pragma unroll
  for (int j = 0; j < 4; ++j) {
    const int R = j * 32 + wv * 8 + lr;
    int ar = rows[seg + blockIdx.y * 128 + R];
    if (ar < 0) ar = 0;  // padding rows: junk compute, dropped downstream
    aptr[j] = A + (size_t)ar * H_DIM + colsw * 8;
  }

  // ---- B staging coords (fp32 -> bf16 transpose, round-2 pattern) ----
  const int n4 = (tid & 31) * 4;
  const int kb = (tid >> 5) * 8;
  const float* BgE = Bg + (size_t)e * H_DIM * I_DIM;  // [K][N] n-contig
  const float* BuE = Bu + (size_t)e * H_DIM * I_DIM;

  floatx4 accg[4][4], accu[4][4];
#pragma unroll
  for (int a = 0; a < 4; ++a)
#pragma unroll
    for (int b = 0; b < 4; ++b) {
      accg[a][b] = (floatx4){0.f, 0.f, 0.f, 0.f};
      accu[a][b] = (floatx4){0.f, 0.f, 0.f, 0.f};
    }

  for (int kt = 0; kt < H_DIM; kt += 64) {
    // ---- stage A via async DMA ----
#pragma unroll
    for (int j = 0; j < 4; ++j)
      gload_lds16(aptr[j] + kt, sA + (j * 32 + wv * 8) * 64);
    // ---- stage B fp32 -> bf16 transposed ----
    {
      const float* bp = BgE + (size_t)(kt + kb) * I_DIM + blockIdx.x * 128 + n4;
      floatx4 r[8];
#pragma unroll
      for (int jj = 0; jj < 8; ++jj) r[jj] = *(const floatx4*)(bp + (size_t)jj * I_DIM);
#pragma unroll
      for (int i = 0; i < 4; ++i) {
        ushort8 p;
#pragma unroll
        for (int jj = 0; jj < 8; ++jj) p[jj] = f2bf(r[jj][i]);
        *(ushort8*)(sBg + (n4 + i) * 72 + kb) = p;
      }
      const float* bq = BuE + (size_t)(kt + kb) * I_DIM + blockIdx.x * 128 + n4;
#pragma unroll
      for (int jj = 0; jj < 8; ++jj) r[jj] = *(const floatx4*)(bq + (size_t)jj * I_DIM);
#pragma unroll
      for (int i = 0; i < 4; ++i) {
        ushort8 p;
#pragma unroll
        for (int jj = 0; jj < 8; ++jj) p[jj] = f2bf(r[jj][i]);
        *(ushort8*)(sBu + (n4 + i) * 72 + kb) = p;
      }
    }
    __syncthreads();
    // ---- compute: 2 k-steps of 32, 64 MFMA per barrier pair ----
#pragma unroll
    for (int ks = 0; ks < 64; ks += 32) {
      const int sbase = ks >> 3;  // A swizzle base (8-elem slots)
      bf16x8 af[4], bfr[4];
#pragma unroll
      for (int fm = 0; fm < 4; ++fm) {
        const int ra = wm + fm * 16 + l15;
        af[fm] = __builtin_bit_cast(bf16x8,
            *(const ushort8*)(sA + ra * 64 + (((q + sbase) ^ (ra & 7)) << 3)));
      }
#pragma unroll
      for (int fn = 0; fn < 4; ++fn)
        bfr[fn] = __builtin_bit_cast(bf16x8,
            *(const ushort8*)(sBg + (wn + fn * 16 + l15) * 72 + ks + q * 8));
#pragma unroll
      for (int fm = 0; fm < 4; ++fm)
#pragma unroll
        for (int fn = 0; fn < 4; ++fn)
          accg[fm][fn] = __builtin_amdgcn_mfma_f32_16x16x32_bf16(af[fm], bfr[fn],
                                                                 accg[fm][fn], 0, 0, 0);
#pragma unroll
      for (int fn = 0; fn < 4; ++fn)
        bfr[fn] = __builtin_bit_cast(bf16x8,
            *(const ushort8*)(sBu + (wn + fn * 16 + l15) * 72 + ks + q * 8));
#pragma unroll
      for (int fm = 0; fm < 4; ++fm)
#pragma unroll
        for (int fn = 0; fn < 4; ++fn)
          accu[fm][fn] = __builtin_amdgcn_mfma_f32_16x16x32_bf16(af[fm], bfr[fn],
                                                                 accu[fm][fn], 0, 0, 0);
    }
    __syncthreads();
  }

  // ---- epilogue: C/D layout col=lane&15, row=(lane>>4)*4+reg ----
#pragma unroll
  for (int fm = 0; fm < 4; ++fm)
#pragma unroll
    for (int fn = 0; fn < 4; ++fn)
#pragma unroll
      for (int rr = 0; rr < 4; ++rr) {
        const int row = wm + fm * 16 + q * 4 + rr;
        const int col = wn + fn * 16 + l15;
        const int gm = blockIdx.y * 128 + row;
        const int gn = blockIdx.x * 128 + col;
        const float g = accg[fm][fn][rr];
        const float u = accu[fm][fn][rr];
        const float s = g / (1.f + __expf(-g));  // silu in f32
        inter[(size_t)(seg + gm) * I_DIM + gn] = f2bf(s * u);
      }
}

// ---------------------------------------------------------------------------
// K6: down grouped GEMM, fp32 weights direct, 2-way n-fusion (128m x 256n,
// two B halves share one staged A -> 64 MFMA per barrier pair).
// A = inter bf16 [PAD_ROWS][I_DIM] (segment rows, no gather).
// B = down_w fp32 [E][I_DIM][H_DIM] (n-contig), transpose-staged like gu.
// Scatters fp32 rows to outp by token.
// ---------------------------------------------------------------------------
__global__ __launch_bounds__(256, 2) void moe_gemm_down(
    const unsigned short* __restrict__ A,
    const float* __restrict__ Bw,
    const int* __restrict__ hdr,
    const int* __restrict__ rows,
    float* __restrict__ outp) {
  const int e = blockIdx.z;
  const int cnt = hdr[e];
  if ((int)blockIdx.y * 128 >= cnt) return;  // uniform early exit
  const int seg = hdr[16 + e];

  const int tid = threadIdx.x;
  const int lane = tid & 63;
  const int wv = tid >> 6;
  const int wm = (wv & 1) * 64;
  const int wn = (wv >> 1) * 64;
  const int q = lane >> 4;
  const int l15 = lane & 15;

  __shared__ unsigned short sA[128 * 64];
  __shared__ unsigned short sB0[128 * 72];
  __shared__ unsigned short sB1[128 * 72];

  const int lr = lane >> 3;
  const int colsw = (lane & 7) ^ lr;
  const unsigned short* aptr[4];
#pragma unroll
  for (int j = 0; j < 4; ++j) {
    const int R = j * 32 + wv * 8 + lr;
    aptr[j] = A + (size_t)(seg + blockIdx.y * 128 + R) * I_DIM + colsw * 8;
  }

  const int n4 = (tid & 31) * 4;
  const int kb = (tid >> 5) * 8;
  const float* Be = Bw + (size_t)e * I_DIM * H_DIM;  // [K=I][N=H] n-contig

  floatx4 acc0[4][4], acc1[4][4];
#pragma unroll
  for (int a = 0; a < 4; ++a)
#pragma unroll
    for (int b = 0; b < 4; ++b) {
      acc0[a][b] = (floatx4){0.f, 0.f, 0.f, 0.f};
      acc1[a][b] = (floatx4){0.f, 0.f, 0.f, 0.f};
    }

  for (int kt = 0; kt < I_DIM; kt += 64) {
#pragma unroll
    for (int j = 0; j < 4; ++j)
      gload_lds16(aptr[j] + kt, sA + (j * 32 + wv * 8) * 64);
    {
      const float* bp = Be + (size_t)(kt + kb) * H_DIM + blockIdx.x * 256 + n4;
      floatx4 r[8];
#pragma unroll
      for (int jj = 0; jj < 8; ++jj) r[jj] = *(const floatx4*)(bp + (size_t)jj * H_DIM);
#pragma unroll
      for (int i = 0; i < 4; ++i) {
        ushort8 p;
#pragma unroll
        for (int jj = 0; jj < 8; ++jj) p[jj] = f2bf(r[jj][i]);
        *(ushort8*)(sB0 + (n4 + i) * 72 + kb) = p;
      }
      const float* bq = bp + 128;
#pragma unroll
      for (int jj = 0; jj < 8; ++jj) r[jj] = *(const floatx4*)(bq + (size_t)jj * H_DIM);
#pragma unroll
      for (int i = 0; i < 4; ++i) {
        ushort8 p;
#pragma unroll
        for (int jj = 0; jj < 8; ++jj) p[jj] = f2bf(r[jj][i]);
        *(ushort8*)(sB1 + (n4 + i) * 72 + kb) = p;
      }
    }
    __syncthreads();
#pragma unroll
    for (int ks = 0; ks < 64; ks += 32) {
      const int sbase = ks >> 3;
      bf16x8 af[4], bfr[4];
#pragma unroll
      for (int fm = 0; fm < 4; ++fm) {
        const int ra = wm + fm * 16 + l15;
        af[fm] = __builtin_bit_cast(bf16x8,
            *(const ushort8*)(sA + ra * 64 + (((q + sbase) ^ (ra & 7)) << 3)));
      }
#pragma unroll
      for (int fn = 0; fn < 4; ++fn)
        bfr[fn] = __builtin_bit_cast(bf16x8,
            *(const ushort8*)(sB0 + (wn + fn * 16 + l15) * 72 + ks + q * 8));
#pragma unroll
      for (int fm = 0; fm < 4; ++fm)
#pragma unroll
        for (int fn = 0; fn < 4; ++fn)
          acc0[fm][fn] = __builtin_amdgcn_mfma_f32_16x16x32_bf16(af[fm], bfr[fn],
                                                                 acc0[fm][fn], 0, 0, 0);
#pragma unroll
      for (int fn = 0; fn < 4; ++fn)
        bfr[fn] = __builtin_bit_cast(bf16x8,
            *(const ushort8*)(sB1 + (wn + fn * 16 + l15) * 72 + ks + q * 8));
#pragma unroll
      for (int fm = 0; fm < 4; ++fm)
#pragma unroll
        for (int fn = 0; fn < 4; ++fn)
          acc1[fm][fn] = __builtin_amdgcn_mfma_f32_16x16x32_bf16(af[fm], bfr[fn],
                                                                 acc1[fm][fn], 0, 0, 0);
    }
    __syncthreads();
  }

  // ---- epilogue: scatter both n-halves by token ----
#pragma unroll
  for (int fm = 0; fm < 4; ++fm)
#pragma unroll
    for (int rr = 0; rr < 4; ++rr) {
      const int row = wm + fm * 16 + q * 4 + rr;
      const int tok = rows[seg + blockIdx.y * 128 + row];
      if (tok < 0) continue;
      float* orow = outp + (size_t)tok * H_DIM + blockIdx.x * 256;
#pragma unroll
      for (int fn = 0; fn < 4; ++fn) {
        const int col = wn + fn * 16 + l15;
        orow[col]       = acc0[fm][fn][rr];
        orow[128 + col] = acc1[fm][fn][rr];
      }
    }
}

// ---------------------------------------------------------------------------
// host launcher
// ---------------------------------------------------------------------------
extern "C" void kernel_launch(void* const* d_in, const int* in_sizes, int n_in,
                              void* d_out, int out_size, void* d_ws, size_t ws_size,
                              hipStream_t stream) {
  const float* hidden   = (const float*)d_in[0];
  const float* router_w = (const float*)d_in[1];
  const float* gate_w   = (const float*)d_in[2];
  const float* up_w     = (const float*)d_in[3];
  const float* down_w   = (const float*)d_in[4];
  float* out = (float*)d_out;

  char* ws = (char*)d_ws;
  // ws layout (bytes):
  //   hdr   @ 0         : 32 ints
  //   idx   @ 1024      : 8192 ints            (32768 B)
  //   rows  @ 33792     : 9216 ints            (36864 B)
  //   x_bf  @ 70656     : 8192*2048 bf16       (33554432 B)
  //   inter @ 33625088  : 9216*4096 bf16       (75497472 B)
  //   total = 109122560 B (~109 MB) -- no weight buffers (prepass deleted)
  int* hdr  = (int*)ws;
  int* idx  = (int*)(ws + 1024);
  int* rows = (int*)(ws + 33792);
  unsigned short* x_bf  = (unsigned short*)(ws + 70656);
  unsigned short* inter = (unsigned short*)(ws + 33625088);

  hipMemsetAsync(hdr, 0, 128, stream);
  router_kernel<<<T_TOKENS / 4, 256, 0, stream>>>(hidden, router_w, x_bf, idx, hdr);
  setup_kernel<<<1, 256, 0, stream>>>(hdr, rows);
  scatter_kernel<<<T_TOKENS / 256, 256, 0, stream>>>(idx, hdr, rows);

  // fused gate+up GEMM (fp32 weights direct): inter = silu(x@gate) * (x@up)
  moe_gemm_gu<<<dim3(I_DIM / 128, 64, E_EXP), 256, 0, stream>>>(
      x_bf, gate_w, up_w, hdr, rows, inter);
  // down GEMM (fp32 weights direct), scatters by token
  moe_gemm_down<<<dim3(H_DIM / 256, 64, E_EXP), 256, 0, stream>>>(
      inter, down_w, hdr, rows, out);
}

// Round 11
// 1434.671 us; speedup vs baseline: 1.3348x; 1.3348x over previous
//
#include <hip/hip_runtime.h>
#include <hip/hip_bf16.h>

// Problem constants
#define T_TOKENS 8192   // SEQ*BS
#define H_DIM 2048
#define I_DIM 4096
#define E_EXP 8
#define PAD_ROWS 9216   // 8192 + 8*128 worst-case padded segment total

typedef __bf16 bf16x8 __attribute__((ext_vector_type(8)));
typedef float floatx4 __attribute__((ext_vector_type(4)));
typedef unsigned short ushort8 __attribute__((ext_vector_type(8)));

__device__ __forceinline__ unsigned short f2bf(float f) {
  // round-to-nearest-even f32 -> bf16 (inputs are finite; no NaN handling needed)
  union { float f; unsigned int i; } c; c.f = f;
  unsigned int x = c.i;
  unsigned int r = x + 0x7fffu + ((x >> 16) & 1u);
  return (unsigned short)(r >> 16);
}

// async global->LDS, 16B per lane. LDS dest = wave-uniform base + lane*16.
// Global source is PER-LANE (guide §5 / m173).
__device__ __forceinline__ void gload_lds16(const void* g, void* l) {
  __builtin_amdgcn_global_load_lds(
      (const __attribute__((address_space(1))) void*)g,
      (__attribute__((address_space(3))) void*)l, 16, 0, 0);
}

// ---------------------------------------------------------------------------
// cvt helper: one block converts an 8k x 1024n slab of fp32 W[K][N] into the
// chunk-tiled bf16 layout [kg=k>>3][ng=n>>4][n&15][k&7] (chunk = 256B).
// NOTE (round-10 lesson): this prepass is NOT optional — in-GEMM fp32
// transpose staging has an inherent ~16-way ds_write bank conflict
// (column-write into row-major tile), measured 890us/6.9e7 conflicts.
// ---------------------------------------------------------------------------
__device__ __forceinline__ void cvt_slab(const float* __restrict__ W,
                                         unsigned short* __restrict__ Wt,
                                         int K, int N, int e, int kg, int nb,
                                         int tid) {
  const int n0 = tid * 4;
  const float* src = W + (size_t)e * K * N + (size_t)kg * 8 * N + nb + n0;
  unsigned short* dst = Wt + (size_t)e * K * N
                        + ((size_t)kg * (N >> 4) + (nb >> 4)) * 128;
  floatx4 a[8];
#pragma unroll
  for (int kk = 0; kk < 8; ++kk)
    a[kk] = __builtin_nontemporal_load((const floatx4*)(src + (size_t)kk * N));
#pragma unroll
  for (int nn = 0; nn < 4; ++nn) {
    const int n = n0 + nn;
    ushort8 o;
#pragma unroll
    for (int kk = 0; kk < 8; ++kk) o[kk] = f2bf(a[kk][nn]);
    *(ushort8*)(dst + (size_t)(n >> 4) * 128 + (n & 15) * 8) = o;
  }
}

// ---------------------------------------------------------------------------
// K1: MEGA pre-pass: router(+x cvt) blocks 0..2047, gate-cvt 2048..10239,
// up-cvt 10240..18431 — independent jobs run concurrently in one dispatch.
// hdr zeroed via hipMemsetAsync before this kernel.
// ---------------------------------------------------------------------------
__global__ __launch_bounds__(256) void router_cvt_kernel(
    const float* __restrict__ x, const float* __restrict__ rw,
    const float* __restrict__ gw, const float* __restrict__ uw,
    unsigned short* __restrict__ xb, int* __restrict__ idx,
    int* __restrict__ hdr, unsigned short* __restrict__ Wg,
    unsigned short* __restrict__ Wu) {
  if (blockIdx.x >= 2048) {
    int bid = blockIdx.x - 2048;
    const float* W = (bid < 8192) ? gw : uw;
    unsigned short* Wt = (bid < 8192) ? Wg : Wu;
    bid &= 8191;
    const int e = bid >> 10;
    const int rem = bid & 1023;
    cvt_slab(W, Wt, H_DIM, I_DIM, e, rem >> 2, (rem & 3) * 1024, threadIdx.x);
    return;
  }
  const int lane = threadIdx.x & 63;
  const int t = blockIdx.x * 4 + (threadIdx.x >> 6);
  const float* xr = x + (size_t)t * H_DIM;
  unsigned short* xbr = xb + (size_t)t * H_DIM;
  float acc[8];
#pragma unroll
  for (int e = 0; e < 8; ++e) acc[e] = 0.f;
#pragma unroll
  for (int j = 0; j < 8; ++j) {
    const int c0 = (lane + j * 64) * 4;
    floatx4 v = *(const floatx4*)(xr + c0);
    ushort4 o;
    o.x = f2bf(v[0]); o.y = f2bf(v[1]); o.z = f2bf(v[2]); o.w = f2bf(v[3]);
    *(ushort4*)(xbr + c0) = o;
#pragma unroll
    for (int cc = 0; cc < 4; ++cc) {
      const float h = v[cc];
      floatx4 r0 = *(const floatx4*)(rw + (size_t)(c0 + cc) * 8);
      floatx4 r1 = *(const floatx4*)(rw + (size_t)(c0 + cc) * 8 + 4);
#pragma unroll
      for (int e = 0; e < 4; ++e) { acc[e] += h * r0[e]; acc[e + 4] += h * r1[e]; }
    }
  }
#pragma unroll
  for (int off = 32; off > 0; off >>= 1)
#pragma unroll
    for (int e = 0; e < 8; ++e) acc[e] += __shfl_xor(acc[e], off, 64);
  if (lane == 0) {
    int best = 0; float bv = acc[0];
#pragma unroll
    for (int e = 1; e < 8; ++e) if (acc[e] > bv) { bv = acc[e]; best = e; }
    idx[t] = best;
    atomicAdd(&hdr[best], 1);
  }
}

// ---------------------------------------------------------------------------
// K2: segment bases (128-aligned) + rows[] sentinel init
// ---------------------------------------------------------------------------
__global__ __launch_bounds__(256) void setup_kernel(int* __restrict__ hdr,
                                                    int* __restrict__ rows) {
  if (threadIdx.x == 0) {
    int b = 0;
    for (int e = 0; e < 8; ++e) {
      hdr[16 + e] = b;
      b += ((hdr[e] + 127) >> 7) << 7;
    }
  }
  for (int i = threadIdx.x; i < PAD_ROWS; i += 256) rows[i] = -1;
}

// ---------------------------------------------------------------------------
// K3: scatter token ids into per-expert segments
// ---------------------------------------------------------------------------
__global__ __launch_bounds__(256) void scatter_kernel(const int* __restrict__ idx,
                                                      int* __restrict__ hdr,
                                                      int* __restrict__ rows) {
  int t = blockIdx.x * 256 + threadIdx.x;
  int e = idx[t];
  int p = atomicAdd(&hdr[8 + e], 1);
  rows[hdr[16 + e] + p] = t;
}

// ---------------------------------------------------------------------------
// K4: fallback down-weight cvt (small ws: runs after gu, into W1)
// ---------------------------------------------------------------------------
__global__ __launch_bounds__(256) void cvt_down_kernel(const float* __restrict__ W,
                                                       unsigned short* __restrict__ Wt) {
  const int bid = blockIdx.x;          // 0..8191
  const int e = bid >> 10;
  const int rem = bid & 1023;
  cvt_slab(W, Wt, I_DIM, H_DIM, e, rem >> 1, (rem & 1) * 1024, threadIdx.x);
}

// ---------------------------------------------------------------------------
// K5: fused gate+up grouped GEMM (round-7 structure, proven). 128x128 tile,
// BK=64, 4 waves, dual acc; 64 MFMA per barrier pair. Epilogue:
// inter = silu(g_f32) * u. A: gload_lds w16 XOR-swizzled source; B:
// chunk-tiled bf16, lane-linear 1KB DMA, conflict-free ds_read_b128.
// EXTRA (big-ws): blockIdx.y in 64..95 = down-weight cvt blocks fused in
// (overlap gu's HBM slack); W3 only read by the LATER down dispatch.
// ---------------------------------------------------------------------------
__global__ __launch_bounds__(256, 2) void moe_gemm_gu(
    const unsigned short* __restrict__ A,
    const unsigned short* __restrict__ Bg,
    const unsigned short* __restrict__ Bu,
    const int* __restrict__ hdr,
    const int* __restrict__ rows,
    unsigned short* __restrict__ inter,
    const float* __restrict__ dw,
    unsigned short* __restrict__ Wd) {
  if (blockIdx.y >= 64) {
    const int cid = (((int)blockIdx.y - 64) * 32 + (int)blockIdx.x) * 8 + (int)blockIdx.z;
    const int e = cid >> 10;
    const int rem = cid & 1023;
    cvt_slab(dw, Wd, I_DIM, H_DIM, e, rem >> 1, (rem & 1) * 1024, threadIdx.x);
    return;
  }
  const int e = blockIdx.z;
  const int cnt = hdr[e];
  if ((int)blockIdx.y * 128 >= cnt) return;  // uniform early exit
  const int seg = hdr[16 + e];

  const int tid = threadIdx.x;
  const int lane = tid & 63;
  const int wv = tid >> 6;
  const int wm = (wv & 1) * 64;
  const int wn = (wv >> 1) * 64;
  const int q = lane >> 4;
  const int l15 = lane & 15;

  __shared__ unsigned short sA[128 * 64];   // [m][64k], slot-swizzled
  __shared__ unsigned short sBg[64 * 128];  // chunk-tiled [8kg][8ng][16][8]
  __shared__ unsigned short sBu[64 * 128];

  const int lr = lane >> 3;
  const int colsw = (lane & 7) ^ lr;
  const unsigned short* aptr[4];
#pragma unroll
  for (int j = 0; j < 4; ++j) {
    const int R = j * 32 + wv * 8 + lr;
    int ar = rows[seg + blockIdx.y * 128 + R];
    if (ar < 0) ar = 0;  // padding rows: junk compute, dropped downstream
    aptr[j] = A + (size_t)ar * H_DIM + colsw * 8;
  }

  const int N16 = I_DIM / 16;
  const int ng0 = blockIdx.x * 8;
  const unsigned short* BgE = Bg + (size_t)e * I_DIM * H_DIM;
  const unsigned short* BuE = Bu + (size_t)e * I_DIM * H_DIM;

  floatx4 accg[4][4], accu[4][4];
#pragma unroll
  for (int a = 0; a < 4; ++a)
#pragma unroll
    for (int b = 0; b < 4; ++b) {
      accg[a][b] = (floatx4){0.f, 0.f, 0.f, 0.f};
      accu[a][b] = (floatx4){0.f, 0.f, 0.f, 0.f};
    }

  const int ubB = q * 1024 + l15 * 8;
  const int wn16o = (wn >> 4) * 128;

  for (int kt = 0; kt < H_DIM; kt += 64) {
#pragma unroll
    for (int j = 0; j < 4; ++j) {
      gload_lds16(aptr[j] + kt, sA + (j * 32 + wv * 8) * 64);
      const int g = j * 4 + wv;
      const int kgg = (kt >> 3) + (g >> 1);
      const size_t so = (size_t)(kgg * N16 + ng0 + (g & 1) * 4) * 128 + lane * 8;
      gload_lds16(BgE + so, sBg + g * 512);
      gload_lds16(BuE + so, sBu + g * 512);
    }
    __syncthreads();
#pragma unroll
    for (int ks = 0; ks < 64; ks += 32) {
      const int sbase = ks >> 3;
      const int bbase = ks * 128 + wn16o + ubB;
      bf16x8 af[4], bfr[4];
#pragma unroll
      for (int fm = 0; fm < 4; ++fm) {
        const int ra = wm + fm * 16 + l15;
        af[fm] = __builtin_bit_cast(bf16x8,
            *(const ushort8*)(sA + ra * 64 + (((q + sbase) ^ (ra & 7)) << 3)));
      }
#pragma unroll
      for (int fn = 0; fn < 4; ++fn)
        bfr[fn] = __builtin_bit_cast(bf16x8,
            *(const ushort8*)(sBg + bbase + fn * 128));
#pragma unroll
      for (int fm = 0; fm < 4; ++fm)
#pragma unroll
        for (int fn = 0; fn < 4; ++fn)
          accg[fm][fn] = __builtin_amdgcn_mfma_f32_16x16x32_bf16(af[fm], bfr[fn],
                                                                 accg[fm][fn], 0, 0, 0);
#pragma unroll
      for (int fn = 0; fn < 4; ++fn)
        bfr[fn] = __builtin_bit_cast(bf16x8,
            *(const ushort8*)(sBu + bbase + fn * 128));
#pragma unroll
      for (int fm = 0; fm < 4; ++fm)
#pragma unroll
        for (int fn = 0; fn < 4; ++fn)
          accu[fm][fn] = __builtin_amdgcn_mfma_f32_16x16x32_bf16(af[fm], bfr[fn],
                                                                 accu[fm][fn], 0, 0, 0);
    }
    __syncthreads();
  }

#pragma unroll
  for (int fm = 0; fm < 4; ++fm)
#pragma unroll
    for (int fn = 0; fn < 4; ++fn)
#pragma unroll
      for (int rr = 0; rr < 4; ++rr) {
        const int row = wm + fm * 16 + q * 4 + rr;
        const int col = wn + fn * 16 + l15;
        const int gm = blockIdx.y * 128 + row;
        const int gn = blockIdx.x * 128 + col;
        const float g = accg[fm][fn][rr];
        const float u = accu[fm][fn][rr];
        const float s = g / (1.f + __expf(-g));  // silu in f32
        inter[(size_t)(seg + gm) * I_DIM + gn] = f2bf(s * u);
      }
}

// ---------------------------------------------------------------------------
// K6a: down grouped GEMM, SPLIT-K x2. Round-9 down had only 512 real blocks
// (2/CU) -> no co-resident block to hide the vmcnt(0)+barrier stall. Split-K
// doubles block count to 1024 (4/CU queue) keeping the proven inner loop
// intact. blockIdx.y = (ytile<<1)|khalf; each half (K=2048) accumulates into
// fp32 partials p[khalf] (alias W1/W2, dead after gu). Add+scatter follows.
// ---------------------------------------------------------------------------
__global__ __launch_bounds__(256, 2) void moe_gemm_down_sk(
    const unsigned short* __restrict__ A,
    const unsigned short* __restrict__ Bt,
    const int* __restrict__ hdr,
    float* __restrict__ p0,
    float* __restrict__ p1) {
  const int e = blockIdx.z;
  const int cnt = hdr[e];
  const int ytile = blockIdx.y >> 1;
  const int khalf = blockIdx.y & 1;
  if (ytile * 128 >= cnt) return;  // uniform early exit
  const int seg = hdr[16 + e];

  const int tid = threadIdx.x;
  const int lane = tid & 63;
  const int wv = tid >> 6;
  const int wm = (wv & 1) * 64;
  const int wn = (wv >> 1) * 64;
  const int q = lane >> 4;
  const int l15 = lane & 15;

  __shared__ unsigned short sA[128 * 64];
  __shared__ unsigned short sB0[64 * 128];
  __shared__ unsigned short sB1[64 * 128];

  const int lr = lane >> 3;
  const int colsw = (lane & 7) ^ lr;
  const unsigned short* aptr[4];
#pragma unroll
  for (int j = 0; j < 4; ++j) {
    const int R = j * 32 + wv * 8 + lr;
    aptr[j] = A + (size_t)(seg + ytile * 128 + R) * I_DIM + colsw * 8;
  }

  const int N16 = H_DIM / 16;
  const int ng0 = blockIdx.x * 16;
  const unsigned short* Be = Bt + (size_t)e * H_DIM * I_DIM;

  floatx4 acc0[4][4], acc1[4][4];
#pragma unroll
  for (int a = 0; a < 4; ++a)
#pragma unroll
    for (int b = 0; b < 4; ++b) {
      acc0[a][b] = (floatx4){0.f, 0.f, 0.f, 0.f};
      acc1[a][b] = (floatx4){0.f, 0.f, 0.f, 0.f};
    }

  const int ubB = q * 1024 + l15 * 8;
  const int wn16o = (wn >> 4) * 128;
  const int k0 = khalf * (I_DIM / 2);

  for (int kt = k0; kt < k0 + I_DIM / 2; kt += 64) {
#pragma unroll
    for (int j = 0; j < 4; ++j) {
      gload_lds16(aptr[j] + kt, sA + (j * 32 + wv * 8) * 64);
      const int g = j * 4 + wv;
      const int kgg = (kt >> 3) + (g >> 1);
      const size_t so0 = (size_t)(kgg * N16 + ng0 + (g & 1) * 4) * 128 + lane * 8;
      const size_t so1 = (size_t)(kgg * N16 + ng0 + 8 + (g & 1) * 4) * 128 + lane * 8;
      gload_lds16(Be + so0, sB0 + g * 512);
      gload_lds16(Be + so1, sB1 + g * 512);
    }
    __syncthreads();
#pragma unroll
    for (int ks = 0; ks < 64; ks += 32) {
      const int sbase = ks >> 3;
      const int bbase = ks * 128 + wn16o + ubB;
      bf16x8 af[4], bfr[4];
#pragma unroll
      for (int fm = 0; fm < 4; ++fm) {
        const int ra = wm + fm * 16 + l15;
        af[fm] = __builtin_bit_cast(bf16x8,
            *(const ushort8*)(sA + ra * 64 + (((q + sbase) ^ (ra & 7)) << 3)));
      }
#pragma unroll
      for (int fn = 0; fn < 4; ++fn)
        bfr[fn] = __builtin_bit_cast(bf16x8,
            *(const ushort8*)(sB0 + bbase + fn * 128));
#pragma unroll
      for (int fm = 0; fm < 4; ++fm)
#pragma unroll
        for (int fn = 0; fn < 4; ++fn)
          acc0[fm][fn] = __builtin_amdgcn_mfma_f32_16x16x32_bf16(af[fm], bfr[fn],
                                                                 acc0[fm][fn], 0, 0, 0);
#pragma unroll
      for (int fn = 0; fn < 4; ++fn)
        bfr[fn] = __builtin_bit_cast(bf16x8,
            *(const ushort8*)(sB1 + bbase + fn * 128));
#pragma unroll
      for (int fm = 0; fm < 4; ++fm)
#pragma unroll
        for (int fn = 0; fn < 4; ++fn)
          acc1[fm][fn] = __builtin_amdgcn_mfma_f32_16x16x32_bf16(af[fm], bfr[fn],
                                                                 acc1[fm][fn], 0, 0, 0);
    }
    __syncthreads();
  }

  // ---- epilogue: write partial (no scatter; padding rows harmless) ----
  float* pp = khalf ? p1 : p0;
#pragma unroll
  for (int fm = 0; fm < 4; ++fm)
#pragma unroll
    for (int rr = 0; rr < 4; ++rr) {
      const int row = wm + fm * 16 + q * 4 + rr;
      float* orow = pp + (size_t)(seg + ytile * 128 + row) * H_DIM + blockIdx.x * 256;
#pragma unroll
      for (int fn = 0; fn < 4; ++fn) {
        const int col = wn + fn * 16 + l15;
        orow[col]       = acc0[fm][fn][rr];
        orow[128 + col] = acc1[fm][fn][rr];
      }
    }
}

// ---------------------------------------------------------------------------
// K6b: add partials + scatter by token. One block per padded row.
// ---------------------------------------------------------------------------
__global__ __launch_bounds__(256) void add_scatter_kernel(
    const float* __restrict__ p0, const float* __restrict__ p1,
    const int* __restrict__ rows, float* __restrict__ outp) {
  const int r = blockIdx.x;
  const int tok = rows[r];
  if (tok < 0) return;
  const floatx4* a = (const floatx4*)(p0 + (size_t)r * H_DIM);
  const floatx4* b = (const floatx4*)(p1 + (size_t)r * H_DIM);
  floatx4* o = (floatx4*)(outp + (size_t)tok * H_DIM);
#pragma unroll
  for (int i = 0; i < 2; ++i) {
    const int c = i * 256 + threadIdx.x;
    o[c] = a[c] + b[c];
  }
}

// ---------------------------------------------------------------------------
// K6c: fallback full-K down GEMM (small-ws path; round-9 kernel)
// ---------------------------------------------------------------------------
__global__ __launch_bounds__(256, 2) void moe_gemm_down(
    const unsigned short* __restrict__ A,
    const unsigned short* __restrict__ Bt,
    const int* __restrict__ hdr,
    const int* __restrict__ rows,
    float* __restrict__ outp) {
  const int e = blockIdx.z;
  const int cnt = hdr[e];
  if ((int)blockIdx.y * 128 >= cnt) return;
  const int seg = hdr[16 + e];

  const int tid = threadIdx.x;
  const int lane = tid & 63;
  const int wv = tid >> 6;
  const int wm = (wv & 1) * 64;
  const int wn = (wv >> 1) * 64;
  const int q = lane >> 4;
  const int l15 = lane & 15;

  __shared__ unsigned short sA[128 * 64];
  __shared__ unsigned short sB0[64 * 128];
  __shared__ unsigned short sB1[64 * 128];

  const int lr = lane >> 3;
  const int colsw = (lane & 7) ^ lr;
  const unsigned short* aptr[4];
#pragma unroll
  for (int j = 0; j < 4; ++j) {
    const int R = j * 32 + wv * 8 + lr;
    aptr[j] = A + (size_t)(seg + blockIdx.y * 128 + R) * I_DIM + colsw * 8;
  }

  const int N16 = H_DIM / 16;
  const int ng0 = blockIdx.x * 16;
  const unsigned short* Be = Bt + (size_t)e * H_DIM * I_DIM;

  floatx4 acc0[4][4], acc1[4][4];
#pragma unroll
  for (int a = 0; a < 4; ++a)
#pragma unroll
    for (int b = 0; b < 4; ++b) {
      acc0[a][b] = (floatx4){0.f, 0.f, 0.f, 0.f};
      acc1[a][b] = (floatx4){0.f, 0.f, 0.f, 0.f};
    }

  const int ubB = q * 1024 + l15 * 8;
  const int wn16o = (wn >> 4) * 128;

  for (int kt = 0; kt < I_DIM; kt += 64) {
#pragma unroll
    for (int j = 0; j < 4; ++j) {
      gload_lds16(aptr[j] + kt, sA + (j * 32 + wv * 8) * 64);
      const int g = j * 4 + wv;
      const int kgg = (kt >> 3) + (g >> 1);
      const size_t so0 = (size_t)(kgg * N16 + ng0 + (g & 1) * 4) * 128 + lane * 8;
      const size_t so1 = (size_t)(kgg * N16 + ng0 + 8 + (g & 1) * 4) * 128 + lane * 8;
      gload_lds16(Be + so0, sB0 + g * 512);
      gload_lds16(Be + so1, sB1 + g * 512);
    }
    __syncthreads();
#pragma unroll
    for (int ks = 0; ks < 64; ks += 32) {
      const int sbase = ks >> 3;
      const int bbase = ks * 128 + wn16o + ubB;
      bf16x8 af[4], bfr[4];
#pragma unroll
      for (int fm = 0; fm < 4; ++fm) {
        const int ra = wm + fm * 16 + l15;
        af[fm] = __builtin_bit_cast(bf16x8,
            *(const ushort8*)(sA + ra * 64 + (((q + sbase) ^ (ra & 7)) << 3)));
      }
#pragma unroll
      for (int fn = 0; fn < 4; ++fn)
        bfr[fn] = __builtin_bit_cast(bf16x8,
            *(const ushort8*)(sB0 + bbase + fn * 128));
#pragma unroll
      for (int fm = 0; fm < 4; ++fm)
#pragma unroll
        for (int fn = 0; fn < 4; ++fn)
          acc0[fm][fn] = __builtin_amdgcn_mfma_f32_16x16x32_bf16(af[fm], bfr[fn],
                                                                 acc0[fm][fn], 0, 0, 0);
#pragma unroll
      for (int fn = 0; fn < 4; ++fn)
        bfr[fn] = __builtin_bit_cast(bf16x8,
            *(const ushort8*)(sB1 + bbase + fn * 128));
#pragma unroll
      for (int fm = 0; fm < 4; ++fm)
#pragma unroll
        for (int fn = 0; fn < 4; ++fn)
          acc1[fm][fn] = __builtin_amdgcn_mfma_f32_16x16x32_bf16(af[fm], bfr[fn],
                                                                 acc1[fm][fn], 0, 0, 0);
    }
    __syncthreads();
  }

#pragma unroll
  for (int fm = 0; fm < 4; ++fm)
#pragma unroll
    for (int rr = 0; rr < 4; ++rr) {
      const int row = wm + fm * 16 + q * 4 + rr;
      const int tok = rows[seg + blockIdx.y * 128 + row];
      if (tok < 0) continue;
      float* orow = outp + (size_t)tok * H_DIM + blockIdx.x * 256;
#pragma unroll
      for (int fn = 0; fn < 4; ++fn) {
        const int col = wn + fn * 16 + l15;
        orow[col]       = acc0[fm][fn][rr];
        orow[128 + col] = acc1[fm][fn][rr];
      }
    }
}

// ---------------------------------------------------------------------------
// host launcher
// ---------------------------------------------------------------------------
extern "C" void kernel_launch(void* const* d_in, const int* in_sizes, int n_in,
                              void* d_out, int out_size, void* d_ws, size_t ws_size,
                              hipStream_t stream) {
  const float* hidden   = (const float*)d_in[0];
  const float* router_w = (const float*)d_in[1];
  const float* gate_w   = (const float*)d_in[2];
  const float* up_w     = (const float*)d_in[3];
  const float* down_w   = (const float*)d_in[4];
  float* out = (float*)d_out;

  char* ws = (char*)d_ws;
  // ws layout (bytes):
  //   hdr   @ 0         : 32 ints
  //   idx   @ 1024      : 8192 ints            (32768 B)
  //   rows  @ 33792     : 9216 ints            (36864 B)
  //   x_bf  @ 70656     : 8192*2048 bf16       (33554432 B)
  //   inter @ 33625088  : 9216*4096 bf16       (75497472 B)
  //   W1    @ 109122560 : 134217728 B  gate tiled; after gu: p0 (75.5MB) +
  //                       p1 head (aliasing into W2, both dead after gu)
  //   W2    @ 243340288 : 134217728 B  up tiled
  //   W3    @ 377558016 : 134217728 B  down tiled (big path)
  //   big total = 511775744 B; fallback total = 377558016 B
  int* hdr  = (int*)ws;
  int* idx  = (int*)(ws + 1024);
  int* rows = (int*)(ws + 33792);
  unsigned short* x_bf  = (unsigned short*)(ws + 70656);
  unsigned short* inter = (unsigned short*)(ws + 33625088);
  unsigned short* W1    = (unsigned short*)(ws + 109122560);
  unsigned short* W2    = (unsigned short*)(ws + 243340288);
  unsigned short* W3    = (unsigned short*)(ws + 377558016);
  float* p0 = (float*)W1;                                   // 75.5 MB
  float* p1 = (float*)(ws + 109122560 + 75497472);          // 75.5 MB (ends in W2)
  const bool big = ws_size >= 511775744ull;

  hipMemsetAsync(hdr, 0, 128, stream);
  // mega pre-pass: router + gate-cvt + up-cvt run concurrently
  router_cvt_kernel<<<2048 + 16384, 256, 0, stream>>>(
      hidden, router_w, gate_w, up_w, x_bf, idx, hdr, W1, W2);
  setup_kernel<<<1, 256, 0, stream>>>(hdr, rows);
  scatter_kernel<<<T_TOKENS / 256, 256, 0, stream>>>(idx, hdr, rows);

  if (big) {
    // gu GEMM with down-weight cvt fused into extra y-rows
    moe_gemm_gu<<<dim3(I_DIM / 128, 96, E_EXP), 256, 0, stream>>>(
        x_bf, W1, W2, hdr, rows, inter, down_w, W3);
    // split-K down: 1024 real blocks (4/CU queue) -> partials -> add+scatter
    moe_gemm_down_sk<<<dim3(H_DIM / 256, 128, E_EXP), 256, 0, stream>>>(
        inter, W3, hdr, p0, p1);
    add_scatter_kernel<<<PAD_ROWS, 256, 0, stream>>>(p0, p1, rows, out);
  } else {
    moe_gemm_gu<<<dim3(I_DIM / 128, 64, E_EXP), 256, 0, stream>>>(
        x_bf, W1, W2, hdr, rows, inter, nullptr, nullptr);
    cvt_down_kernel<<<8192, 256, 0, stream>>>(down_w, W1);
    moe_gemm_down<<<dim3(H_DIM / 256, 64, E_EXP), 256, 0, stream>>>(
        inter, W1, hdr, rows, out);
  }
}